// Round 8
// baseline (335.775 us; speedup 1.0000x reference)
//
#include <hip/hip_runtime.h>
#include <hip/hip_bf16.h>
#include <stdint.h>

// out[M,N] = x[M,K] @ (base + coeff*(2*mask-1))[K,N]
#define M_DIM 8192
#define K_DIM 4096
#define N_DIM 4096
#define NT (K_DIM / 64)   // 64 K-tiles of BK=64

typedef __attribute__((ext_vector_type(8))) short short8;
typedef __attribute__((ext_vector_type(16))) float f32x16;
typedef unsigned short ushort_t;

typedef const __attribute__((address_space(1))) unsigned int as1const_u32;
typedef __attribute__((address_space(3))) unsigned int as3_u32;

__device__ __forceinline__ unsigned short f2bf(float f) {
  unsigned int u = __float_as_uint(f);
  u += 0x7FFF + ((u >> 16) & 1);   // round-to-nearest-even
  return (unsigned short)(u >> 16);
}

// ---------- prep 1: x (f32) -> bf16, vectorized ----------
__global__ void cvt_x_kernel(const float* __restrict__ x,
                             ushort_t* __restrict__ xb, long n8) {
  long i = (long)blockIdx.x * blockDim.x + threadIdx.x;
  long stride = (long)gridDim.x * blockDim.x;
  for (; i < n8; i += stride) {
    const float4* p = (const float4*)(x + i * 8);
    float4 v0 = p[0], v1 = p[1];
    short8 o;
    o[0] = (short)f2bf(v0.x); o[1] = (short)f2bf(v0.y);
    o[2] = (short)f2bf(v0.z); o[3] = (short)f2bf(v0.w);
    o[4] = (short)f2bf(v1.x); o[5] = (short)f2bf(v1.y);
    o[6] = (short)f2bf(v1.z); o[7] = (short)f2bf(v1.w);
    *(short8*)(xb + i * 8) = o;
  }
}

// ---------- prep 2: Wt[n][k] = bf16(base[k][n] + coeff*sign) ----------
__global__ void make_wt_kernel(const float* __restrict__ base,
                               const int* __restrict__ mask,
                               const float* __restrict__ coeffp,
                               ushort_t* __restrict__ wt) {
  __shared__ ushort_t tile[32][33];
  const float c = *coeffp;
  const int n0 = blockIdx.x * 32, k0 = blockIdx.y * 32;
  const int tx = threadIdx.x, ty = threadIdx.y;
#pragma unroll
  for (int r = 0; r < 4; ++r) {
    int k = k0 + ty + r * 8;
    int n = n0 + tx;
    size_t idx = (size_t)k * N_DIM + n;
    float s = mask[idx] ? c : -c;
    tile[ty + r * 8][tx] = f2bf(base[idx] + s);
  }
  __syncthreads();
#pragma unroll
  for (int r = 0; r < 4; ++r) {
    int n = n0 + ty + r * 8;
    int k = k0 + tx;
    wt[(size_t)n * K_DIM + k] = tile[tx][ty + r * 8];
  }
}

// ---------- 256x256 bf16 GEMM: R3 4-phase skeleton + 32x32x16 MFMA ----------
// Fragments: A row = mi*64 + wm*32 + (lane&31)  (mi 0..3)  -> A.h0 = mi0-1 (p1),
//            A.h1 = mi2-3 (p3).  B col = ni*128 + wn*32 + (lane&31) (ni 0..1)
//            -> B.h0 = ni0 (read p1), B.h1 = ni1 (read p2).
// Region->read-phase mapping identical to R3, so R3's proven stage stream holds:
//   p1:(t+1,B,h1)  p2:(t+1,A,h1)  p3:(t+2,A,h0)  p4:(t+2,B,h0)
// Waits: vmcnt(6) at p2-end and p4-end (forcing chain re-derived, min lead 3
// phases).  Tail: loop t<NT-2, stage 2 missing halves, vmcnt(0)+BAR, 2 peeled
// stage-free tiles (round-2 fix preserved).
#define FENCE asm volatile("" ::: "memory")
#define BAR   do { FENCE; __builtin_amdgcn_s_barrier(); FENCE; } while (0)
#define VW6   asm volatile("s_waitcnt vmcnt(6)" ::: "memory")
#define VW0   asm volatile("s_waitcnt vmcnt(0)" ::: "memory")

__global__ __launch_bounds__(512, 2) void gemm_bf16_256(
    const ushort_t* __restrict__ Xb,
    const ushort_t* __restrict__ Wt,
    float* __restrict__ out) {
  __shared__ ushort_t Al[2][256][64];   // 64 KiB
  __shared__ ushort_t Bl[2][256][64];   // 64 KiB

  const int tid = threadIdx.x;
  const int lane = tid & 63;
  const int w = tid >> 6;               // wave 0..7
  const int wm = w >> 2, wn = w & 3;    // 2M x 4N
  const int l31 = lane & 31, l5 = lane >> 5;

  // T1: bijective XCD swizzle (512 % 8 == 0)
  const int bid = blockIdx.x;
  const int swz = (bid & 7) * 64 + (bid >> 3);
  const int bm = (swz >> 4) * 256;
  const int bn = (swz & 15) * 256;

  // staging: thread covers half-rows w*8+(lane>>3) and +64; LDS slot lane&7;
  // source chunk = slot ^ (row&7)  (pre-swizzled source; read applies same XOR)
  const int rh0 = w * 8 + (lane >> 3);
  const int srcslot = (lane & 7) ^ ((lane >> 3) & 7);
  const ushort_t* Ag = Xb + (size_t)(bm + rh0) * K_DIM + srcslot * 8;
  const ushort_t* Bg = Wt + (size_t)(bn + rh0) * K_DIM + srcslot * 8;
  char* AlB = (char*)&Al[0][0][0];
  char* BlB = (char*)&Bl[0][0][0];
  const int ldsw = w * 1024;

#define STAGE(Og, Lb, u, h) do {                                                   \
    const ushort_t* _s0 = (Og) + (size_t)((h) * 128) * K_DIM + (size_t)(u) * 64;   \
    __builtin_amdgcn_global_load_lds((as1const_u32*)_s0,                           \
        (as3_u32*)((Lb) + ((u) & 1) * 32768 + (h) * 16384 + ldsw), 16, 0, 0);      \
    __builtin_amdgcn_global_load_lds((as1const_u32*)(_s0 + (size_t)64 * K_DIM),    \
        (as3_u32*)((Lb) + ((u) & 1) * 32768 + (h) * 16384 + ldsw + 8192), 16, 0, 0); \
  } while (0)

  // read addressing: row*128 + (((kk*2 + l5) ^ (row&7)) * 16); row&7 == lane&7
  const int arow = (wm * 32 + l31) << 7;      // A row-base byte (mi adds mi*8192)
  const int brow = (wn * 32 + l31) << 7;      // B row-base byte (ni adds ni*16384)
  const int sw32[4] = { (((0 * 2 + l5) ^ (lane & 7)) << 4),
                        (((1 * 2 + l5) ^ (lane & 7)) << 4),
                        (((2 * 2 + l5) ^ (lane & 7)) << 4),
                        (((3 * 2 + l5) ^ (lane & 7)) << 4) };

#define LDA32(bt, mi, kk) (*(const short8*)(AlB + (bt) * 32768 + (mi) * 8192 + arow + sw32[kk]))
#define LDB32(bt, ni, kk) (*(const short8*)(BlB + (bt) * 32768 + (ni) * 16384 + brow + sw32[kk]))
#define MFMA32(a, b, c) __builtin_amdgcn_mfma_f32_32x32x16_bf16(a, b, c, 0, 0, 0)

  f32x16 acc[4][2] = {};                // [mi][ni], 128 VGPR
  short8 Ar[2][4];                      // current A mi-pair x kk
  short8 Br0[4], Br1[4];                // B ni0 / ni1 x kk

#define RD_A2(bt, mi0)                                                             \
  _Pragma("unroll")                                                                \
  for (int mi = 0; mi < 2; ++mi)                                                   \
    _Pragma("unroll")                                                              \
    for (int kk = 0; kk < 4; ++kk) Ar[mi][kk] = LDA32(bt, (mi0) + mi, kk);
#define RD_B(dst, bt, ni)                                                          \
  _Pragma("unroll")                                                                \
  for (int kk = 0; kk < 4; ++kk) dst[kk] = LDB32(bt, ni, kk);
// 8 MFMA: acc[mb][nb], acc[mb+1][nb] over kk 0..3 (2 interleaved chains)
#define MMQ32(mb, nb, Bset)                                                        \
  _Pragma("unroll")                                                                \
  for (int kk = 0; kk < 4; ++kk)                                                   \
    _Pragma("unroll")                                                              \
    for (int mi = 0; mi < 2; ++mi)                                                 \
      acc[(mb) + mi][nb] = MFMA32(Ar[mi][kk], Bset[kk], acc[(mb) + mi][nb]);

  // prologue: tile0 all 4 halves + tile1 {A.h0,B.h0}; vmcnt(6) -> first 3 halves
  // landed (A.h0,B.h0,B.h1 of tile0); A.h1(0) forced later at p2(0)'s VW6.
  STAGE(Ag, AlB, 0, 0); STAGE(Bg, BlB, 0, 0);
  STAGE(Bg, BlB, 0, 1); STAGE(Ag, AlB, 0, 1);
  STAGE(Ag, AlB, 1, 0); STAGE(Bg, BlB, 1, 0);
  VW6; BAR;

  for (int t = 0; t < NT - 2; ++t) {
    const int bt = t & 1;

    // ---- p1: read A mi0-1 (8) + B ni0 (4); stage (t+1,B,h1); 8 MFMA (mi0-1,ni0) ----
    RD_A2(bt, 0);
    RD_B(Br0, bt, 0);
    STAGE(Bg, BlB, t + 1, 1);
    BAR;
    __builtin_amdgcn_s_setprio(1);
    MMQ32(0, 0, Br0);
    __builtin_amdgcn_s_setprio(0);
    BAR;

    // ---- p2: read B ni1 (4); stage (t+1,A,h1); 8 MFMA (mi0-1,ni1); VW6 ----
    RD_B(Br1, bt, 1);
    STAGE(Ag, AlB, t + 1, 1);
    BAR;
    __builtin_amdgcn_s_setprio(1);
    MMQ32(0, 1, Br1);
    __builtin_amdgcn_s_setprio(0);
    VW6; BAR;

    // ---- p3: read A mi2-3 (8); stage (t+2,A,h0); 8 MFMA (mi2-3,ni0) ----
    RD_A2(bt, 2);
    STAGE(Ag, AlB, t + 2, 0);
    BAR;
    __builtin_amdgcn_s_setprio(1);
    MMQ32(2, 0, Br0);
    __builtin_amdgcn_s_setprio(0);
    BAR;

    // ---- p4: stage (t+2,B,h0); 8 MFMA (mi2-3,ni1); VW6 ----
    STAGE(Bg, BlB, t + 2, 0);
    BAR;
    __builtin_amdgcn_s_setprio(1);
    MMQ32(2, 1, Br1);
    __builtin_amdgcn_s_setprio(0);
    VW6; BAR;
  }

  // ---- tail: stage 2 missing halves of tile NT-1, drain, 2 peeled tiles ----
  STAGE(Bg, BlB, NT - 1, 1);
  STAGE(Ag, AlB, NT - 1, 1);
  VW0; BAR;
#pragma unroll
  for (int tt = 0; tt < 2; ++tt) {
    const int bt = (NT - 2 + tt) & 1;
    RD_A2(bt, 0);
    RD_B(Br0, bt, 0);
    RD_B(Br1, bt, 1);
    MMQ32(0, 0, Br0);
    MMQ32(0, 1, Br1);
    RD_A2(bt, 2);
    MMQ32(2, 0, Br0);
    MMQ32(2, 1, Br1);
  }

  // epilogue: 32x32 C/D layout col=lane&31, row=(reg&3)+8*(reg>>2)+4*(lane>>5) [m74/m101]
#pragma unroll
  for (int mi = 0; mi < 4; ++mi)
#pragma unroll
    for (int ni = 0; ni < 2; ++ni) {
      const int gr = bm + mi * 64 + wm * 32 + l5 * 4;
      const int gc = bn + ni * 128 + wn * 32 + l31;
      float* o = out + (size_t)gr * N_DIM + gc;
#pragma unroll
      for (int r = 0; r < 16; ++r) {
        const int rowf = (r & 3) + 8 * (r >> 2);
        o[(size_t)rowf * N_DIM] = acc[mi][ni][r];
      }
    }
}

// ---------- fallback (tiny workspace): exact f32 tiled GEMM ----------
__global__ void gemm_f32_fallback(const float* __restrict__ x,
                                  const float* __restrict__ base,
                                  const float* __restrict__ coeffp,
                                  const int* __restrict__ mask,
                                  float* __restrict__ out) {
  __shared__ float As[32][33];
  __shared__ float Bs[32][33];
  const float c = *coeffp;
  const int tx = threadIdx.x, ty = threadIdx.y;
  const int row = blockIdx.y * 32 + ty, col = blockIdx.x * 32 + tx;
  float acc = 0.f;
  for (int kt = 0; kt < K_DIM; kt += 32) {
    As[ty][tx] = x[(size_t)row * K_DIM + kt + tx];
    size_t bidx = (size_t)(kt + ty) * N_DIM + col;
    Bs[ty][tx] = base[bidx] + (mask[bidx] ? c : -c);
    __syncthreads();
#pragma unroll
    for (int k = 0; k < 32; ++k) acc += As[ty][k] * Bs[k][tx];
    __syncthreads();
  }
  out[(size_t)row * N_DIM + col] = acc;
}

extern "C" void kernel_launch(void* const* d_in, const int* in_sizes, int n_in,
                              void* d_out, int out_size, void* d_ws, size_t ws_size,
                              hipStream_t stream) {
  const float* x     = (const float*)d_in[0];
  const float* base  = (const float*)d_in[1];
  const float* coeff = (const float*)d_in[2];
  const int*   mask  = (const int*)d_in[3];
  float* out = (float*)d_out;

  const size_t xb_bytes = (size_t)M_DIM * K_DIM * sizeof(ushort_t);  // 64 MiB
  const size_t wt_bytes = (size_t)K_DIM * N_DIM * sizeof(ushort_t);  // 32 MiB

  if (ws_size >= xb_bytes + wt_bytes) {
    ushort_t* xb = (ushort_t*)d_ws;
    ushort_t* wt = (ushort_t*)((char*)d_ws + xb_bytes);
    long n8 = (long)M_DIM * K_DIM / 8;
    cvt_x_kernel<<<4096, 256, 0, stream>>>(x, xb, n8);
    make_wt_kernel<<<dim3(N_DIM / 32, K_DIM / 32), dim3(32, 8), 0, stream>>>(base, mask, coeff, wt);
    gemm_bf16_256<<<512, 512, 0, stream>>>(xb, wt, out);
  } else {
    gemm_f32_fallback<<<dim3(N_DIM / 32, M_DIM / 32), dim3(32, 32), 0, stream>>>(x, base, coeff, mask, out);
  }
}

// Round 9
// 329.293 us; speedup vs baseline: 1.0197x; 1.0197x over previous
//
#include <hip/hip_runtime.h>
#include <hip/hip_bf16.h>
#include <stdint.h>

// out[M,N] = x[M,K] @ (base + coeff*(2*mask-1))[K,N]
#define M_DIM 8192
#define K_DIM 4096
#define N_DIM 4096
#define NT (K_DIM / 64)   // 64 K-tiles of BK=64

typedef __attribute__((ext_vector_type(8))) short short8;
typedef __attribute__((ext_vector_type(4))) float f32x4;
typedef unsigned short ushort_t;

typedef const __attribute__((address_space(1))) unsigned int as1const_u32;
typedef __attribute__((address_space(3))) unsigned int as3_u32;

__device__ __forceinline__ unsigned short f2bf(float f) {
  unsigned int u = __float_as_uint(f);
  u += 0x7FFF + ((u >> 16) & 1);   // round-to-nearest-even
  return (unsigned short)(u >> 16);
}

// ---------- prep 1: x (f32) -> bf16, vectorized ----------
__global__ void cvt_x_kernel(const float* __restrict__ x,
                             ushort_t* __restrict__ xb, long n8) {
  long i = (long)blockIdx.x * blockDim.x + threadIdx.x;
  long stride = (long)gridDim.x * blockDim.x;
  for (; i < n8; i += stride) {
    const float4* p = (const float4*)(x + i * 8);
    float4 v0 = p[0], v1 = p[1];
    short8 o;
    o[0] = (short)f2bf(v0.x); o[1] = (short)f2bf(v0.y);
    o[2] = (short)f2bf(v0.z); o[3] = (short)f2bf(v0.w);
    o[4] = (short)f2bf(v1.x); o[5] = (short)f2bf(v1.y);
    o[6] = (short)f2bf(v1.z); o[7] = (short)f2bf(v1.w);
    *(short8*)(xb + i * 8) = o;
  }
}

// ---------- prep 2: Wt[n][k] = bf16(base[k][n] + coeff*sign) ----------
__global__ void make_wt_kernel(const float* __restrict__ base,
                               const int* __restrict__ mask,
                               const float* __restrict__ coeffp,
                               ushort_t* __restrict__ wt) {
  __shared__ ushort_t tile[32][33];
  const float c = *coeffp;
  const int n0 = blockIdx.x * 32, k0 = blockIdx.y * 32;
  const int tx = threadIdx.x, ty = threadIdx.y;
#pragma unroll
  for (int r = 0; r < 4; ++r) {
    int k = k0 + ty + r * 8;
    int n = n0 + tx;
    size_t idx = (size_t)k * N_DIM + n;
    float s = mask[idx] ? c : -c;
    tile[ty + r * 8][tx] = f2bf(base[idx] + s);
  }
  __syncthreads();
#pragma unroll
  for (int r = 0; r < 4; ++r) {
    int n = n0 + ty + r * 8;
    int k = k0 + tx;
    wt[(size_t)n * K_DIM + k] = tile[tx][ty + r * 8];
  }
}

// ---------- 256x256 bf16 GEMM: R3 4-phase structure, minimal wait set ----------
// Stage stream (2 loads each): p1:(t+1,B,h1) p2:(t+1,A,h1) p3:(t+2,A,h0) p4:(t+2,B,h0).
// Waits: vmcnt(6) at p2-end and p4-end ONLY (p1-end wait proven redundant):
//   p1(t) reads Ah0[p3(t-2)], Bh0[p4(t-2)] -> forced at p4(t-1)-end (>=4th newest)
//   p2(t) reads Bh1[p1(t-1)]               -> forced at p4(t-1)-end (4th newest)
//   p3(t) reads Ah1[p2(t-1)]               -> forced at p2(t)-end   (4th newest)
// All leads >= 3 phases. lgkmcnt(8) pre-drain before p1's barrier (12 ds_reads).
// Tail (round-2 fix): STAGE guards u<NT; after loop, vmcnt(0)+BAR then a peeled
// stage-free last K-tile.
#define FENCE asm volatile("" ::: "memory")
#define BAR   do { FENCE; __builtin_amdgcn_s_barrier(); FENCE; } while (0)
#define VW6   asm volatile("s_waitcnt vmcnt(6)" ::: "memory")
#define VW4   asm volatile("s_waitcnt vmcnt(4)" ::: "memory")
#define VW0   asm volatile("s_waitcnt vmcnt(0)" ::: "memory")
#define LGK8  asm volatile("s_waitcnt lgkmcnt(8)" ::: "memory")

__global__ __launch_bounds__(512, 2) void gemm_bf16_256(
    const ushort_t* __restrict__ Xb,
    const ushort_t* __restrict__ Wt,
    float* __restrict__ out) {
  __shared__ ushort_t Al[2][256][64];   // 64 KiB
  __shared__ ushort_t Bl[2][256][64];   // 64 KiB

  const int tid = threadIdx.x;
  const int lane = tid & 63;
  const int w = tid >> 6;               // wave 0..7
  const int wm = w >> 2, wn = w & 3;    // 2M x 4N
  const int lrow = lane & 15, kg = lane >> 4;

  // T1: bijective XCD swizzle (512 % 8 == 0)
  const int bid = blockIdx.x;
  const int swz = (bid & 7) * 64 + (bid >> 3);
  const int bm = (swz >> 4) * 256;
  const int bn = (swz & 15) * 256;

  // staging: thread covers half-rows w*8+(lane>>3) and +64; LDS slot lane&7;
  // source chunk = slot ^ (row&7)  (pre-swizzled source; read applies same XOR)
  const int rh0 = w * 8 + (lane >> 3);
  const int srcslot = (lane & 7) ^ ((lane >> 3) & 7);
  const ushort_t* Ag = Xb + (size_t)(bm + rh0) * K_DIM + srcslot * 8;
  const ushort_t* Bg = Wt + (size_t)(bn + rh0) * K_DIM + srcslot * 8;
  char* AlB = (char*)&Al[0][0][0];
  char* BlB = (char*)&Bl[0][0][0];
  const int ldsw = w * 1024;

#define STAGE(Og, Lb, u, h) do { if ((u) < NT) {                                   \
    const ushort_t* _s0 = (Og) + (size_t)((h) * 128) * K_DIM + (size_t)(u) * 64;   \
    __builtin_amdgcn_global_load_lds((as1const_u32*)_s0,                           \
        (as3_u32*)((Lb) + ((u) & 1) * 32768 + (h) * 16384 + ldsw), 16, 0, 0);      \
    __builtin_amdgcn_global_load_lds((as1const_u32*)(_s0 + (size_t)64 * K_DIM),    \
        (as3_u32*)((Lb) + ((u) & 1) * 32768 + (h) * 16384 + ldsw + 8192), 16, 0, 0); \
  } } while (0)

  // LDS read addresses (byte): row*128 + ((kk*4+kg)^(lrow&7))*16
  const int arow = (wm * 16 + lrow) << 7;
  const int brow = (wn * 16 + lrow) << 7;
  const int sw0 = ((0 + kg) ^ (lrow & 7)) << 4;
  const int sw1 = ((4 + kg) ^ (lrow & 7)) << 4;

#define LDA(bt, mi, kk) (*(const short8*)(AlB + (bt) * 32768 + (mi) * 4096 + arow + ((kk) ? sw1 : sw0)))
#define LDB(bt, ni, kk) (*(const short8*)(BlB + (bt) * 32768 + (ni) * 8192 + brow + ((kk) ? sw1 : sw0)))
#define MFMA(a, b, c) __builtin_amdgcn_mfma_f32_16x16x32_bf16(a, b, c, 0, 0, 0)

  f32x4 acc[8][4] = {};
  short8 Ar[4][2], Br[4][2];

  // prologue: tile 0 all 4 halves + tile 1 h0 halves; vmcnt(4) -> tile-0 landed
  STAGE(Ag, AlB, 0, 0); STAGE(Bg, BlB, 0, 0);
  STAGE(Bg, BlB, 0, 1); STAGE(Ag, AlB, 0, 1);
  STAGE(Ag, AlB, 1, 0); STAGE(Bg, BlB, 1, 0);
  VW4; BAR;

  for (int t = 0; t < NT - 1; ++t) {
    const int bt = t & 1;

    // ---- phase 1: stage (t+1,B,h1); read Ah0(mi0-3)+Bh0(ni0-1); MFMA (lo,lo) ----
    STAGE(Bg, BlB, t + 1, 1);
#pragma unroll
    for (int mi = 0; mi < 4; ++mi) { Ar[mi][0] = LDA(bt, mi, 0); Ar[mi][1] = LDA(bt, mi, 1); }
#pragma unroll
    for (int ni = 0; ni < 2; ++ni) { Br[ni][0] = LDB(bt, ni, 0); Br[ni][1] = LDB(bt, ni, 1); }
    LGK8;          // pre-drain 4 oldest of the 12 ds_reads during barrier window
    BAR;
    __builtin_amdgcn_s_setprio(1);
#pragma unroll
    for (int mi = 0; mi < 4; ++mi)
#pragma unroll
      for (int ni = 0; ni < 2; ++ni) {
        acc[mi][ni] = MFMA(Ar[mi][0], Br[ni][0], acc[mi][ni]);
        acc[mi][ni] = MFMA(Ar[mi][1], Br[ni][1], acc[mi][ni]);
      }
    __builtin_amdgcn_s_setprio(0);
    BAR;           // (p1-end vmcnt removed: proven redundant)

    // ---- phase 2: stage (t+1,A,h1); read Bh1(ni2-3); MFMA (lo,hi); VW6 ----
    STAGE(Ag, AlB, t + 1, 1);
#pragma unroll
    for (int ni = 2; ni < 4; ++ni) { Br[ni][0] = LDB(bt, ni, 0); Br[ni][1] = LDB(bt, ni, 1); }
    BAR;
    __builtin_amdgcn_s_setprio(1);
#pragma unroll
    for (int mi = 0; mi < 4; ++mi)
#pragma unroll
      for (int ni = 2; ni < 4; ++ni) {
        acc[mi][ni] = MFMA(Ar[mi][0], Br[ni][0], acc[mi][ni]);
        acc[mi][ni] = MFMA(Ar[mi][1], Br[ni][1], acc[mi][ni]);
      }
    __builtin_amdgcn_s_setprio(0);
    VW6; BAR;

    // ---- phase 3: stage (t+2,A,h0); read Ah1(mi4-7); MFMA (hi,lo) ----
    STAGE(Ag, AlB, t + 2, 0);
#pragma unroll
    for (int mi = 0; mi < 4; ++mi) { Ar[mi][0] = LDA(bt, mi + 4, 0); Ar[mi][1] = LDA(bt, mi + 4, 1); }
    BAR;
    __builtin_amdgcn_s_setprio(1);
#pragma unroll
    for (int mi = 0; mi < 4; ++mi)
#pragma unroll
      for (int ni = 0; ni < 2; ++ni) {
        acc[mi + 4][ni] = MFMA(Ar[mi][0], Br[ni][0], acc[mi + 4][ni]);
        acc[mi + 4][ni] = MFMA(Ar[mi][1], Br[ni][1], acc[mi + 4][ni]);
      }
    __builtin_amdgcn_s_setprio(0);
    BAR;

    // ---- phase 4: stage (t+2,B,h0); MFMA (hi,hi); VW6 ----
    STAGE(Bg, BlB, t + 2, 0);
    BAR;
    __builtin_amdgcn_s_setprio(1);
#pragma unroll
    for (int mi = 0; mi < 4; ++mi)
#pragma unroll
      for (int ni = 2; ni < 4; ++ni) {
        acc[mi + 4][ni] = MFMA(Ar[mi][0], Br[ni][0], acc[mi + 4][ni]);
        acc[mi + 4][ni] = MFMA(Ar[mi][1], Br[ni][1], acc[mi + 4][ni]);
      }
    __builtin_amdgcn_s_setprio(0);
    VW6; BAR;
  }

  // ---- peeled last K-tile: drain ALL DMA, then stage-free compute ----
  VW0; BAR;
  {
    const int bt = (NT - 1) & 1;
#pragma unroll
    for (int mi = 0; mi < 4; ++mi) { Ar[mi][0] = LDA(bt, mi, 0); Ar[mi][1] = LDA(bt, mi, 1); }
#pragma unroll
    for (int ni = 0; ni < 4; ++ni) { Br[ni][0] = LDB(bt, ni, 0); Br[ni][1] = LDB(bt, ni, 1); }
#pragma unroll
    for (int mi = 0; mi < 4; ++mi)
#pragma unroll
      for (int ni = 0; ni < 4; ++ni) {
        acc[mi][ni] = MFMA(Ar[mi][0], Br[ni][0], acc[mi][ni]);
        acc[mi][ni] = MFMA(Ar[mi][1], Br[ni][1], acc[mi][ni]);
      }
#pragma unroll
    for (int mi = 0; mi < 4; ++mi) { Ar[mi][0] = LDA(bt, mi + 4, 0); Ar[mi][1] = LDA(bt, mi + 4, 1); }
#pragma unroll
    for (int mi = 0; mi < 4; ++mi)
#pragma unroll
      for (int ni = 0; ni < 4; ++ni) {
        acc[mi + 4][ni] = MFMA(Ar[mi][0], Br[ni][0], acc[mi + 4][ni]);
        acc[mi + 4][ni] = MFMA(Ar[mi][1], Br[ni][1], acc[mi + 4][ni]);
      }
  }

  // epilogue: C/D layout col=lane&15, row=(lane>>4)*4+r  [m89/m91]
#pragma unroll
  for (int mi = 0; mi < 8; ++mi)
#pragma unroll
    for (int ni = 0; ni < 4; ++ni) {
      const int gr = bm + mi * 32 + wm * 16 + kg * 4;
      const int gc = bn + ni * 64 + wn * 16 + lrow;
      float* o = out + (size_t)gr * N_DIM + gc;
#pragma unroll
      for (int r = 0; r < 4; ++r) o[(size_t)r * N_DIM] = acc[mi][ni][r];
    }
}

// ---------- fallback (tiny workspace): exact f32 tiled GEMM ----------
__global__ void gemm_f32_fallback(const float* __restrict__ x,
                                  const float* __restrict__ base,
                                  const float* __restrict__ coeffp,
                                  const int* __restrict__ mask,
                                  float* __restrict__ out) {
  __shared__ float As[32][33];
  __shared__ float Bs[32][33];
  const float c = *coeffp;
  const int tx = threadIdx.x, ty = threadIdx.y;
  const int row = blockIdx.y * 32 + ty, col = blockIdx.x * 32 + tx;
  float acc = 0.f;
  for (int kt = 0; kt < K_DIM; kt += 32) {
    As[ty][tx] = x[(size_t)row * K_DIM + kt + tx];
    size_t bidx = (size_t)(kt + ty) * N_DIM + col;
    Bs[ty][tx] = base[bidx] + (mask[bidx] ? c : -c);
    __syncthreads();
#pragma unroll
    for (int k = 0; k < 32; ++k) acc += As[ty][k] * Bs[k][tx];
    __syncthreads();
  }
  out[(size_t)row * N_DIM + col] = acc;
}

extern "C" void kernel_launch(void* const* d_in, const int* in_sizes, int n_in,
                              void* d_out, int out_size, void* d_ws, size_t ws_size,
                              hipStream_t stream) {
  const float* x     = (const float*)d_in[0];
  const float* base  = (const float*)d_in[1];
  const float* coeff = (const float*)d_in[2];
  const int*   mask  = (const int*)d_in[3];
  float* out = (float*)d_out;

  const size_t xb_bytes = (size_t)M_DIM * K_DIM * sizeof(ushort_t);  // 64 MiB
  const size_t wt_bytes = (size_t)K_DIM * N_DIM * sizeof(ushort_t);  // 32 MiB

  if (ws_size >= xb_bytes + wt_bytes) {
    ushort_t* xb = (ushort_t*)d_ws;
    ushort_t* wt = (ushort_t*)((char*)d_ws + xb_bytes);
    long n8 = (long)M_DIM * K_DIM / 8;
    cvt_x_kernel<<<4096, 256, 0, stream>>>(x, xb, n8);
    make_wt_kernel<<<dim3(N_DIM / 32, K_DIM / 32), dim3(32, 8), 0, stream>>>(base, mask, coeff, wt);
    gemm_bf16_256<<<512, 512, 0, stream>>>(xb, wt, out);
  } else {
    gemm_f32_fallback<<<dim3(N_DIM / 32, M_DIM / 32), dim3(32, 32), 0, stream>>>(x, base, coeff, mask, out);
  }
}

// Round 10
// 328.304 us; speedup vs baseline: 1.0228x; 1.0030x over previous
//
#include <hip/hip_runtime.h>
#include <hip/hip_bf16.h>
#include <stdint.h>

// out[M,N] = x[M,K] @ (base + coeff*(2*mask-1))[K,N]
#define M_DIM 8192
#define K_DIM 4096
#define N_DIM 4096
#define NT (K_DIM / 64)   // 64 K-tiles of BK=64

typedef __attribute__((ext_vector_type(8))) short short8;
typedef __attribute__((ext_vector_type(4))) float f32x4;
typedef unsigned short ushort_t;

typedef const __attribute__((address_space(1))) unsigned int as1const_u32;
typedef __attribute__((address_space(3))) unsigned int as3_u32;

__device__ __forceinline__ unsigned short f2bf(float f) {
  unsigned int u = __float_as_uint(f);
  u += 0x7FFF + ((u >> 16) & 1);   // round-to-nearest-even
  return (unsigned short)(u >> 16);
}

// ---------- prep 1: x (f32) -> bf16, vectorized ----------
__global__ void cvt_x_kernel(const float* __restrict__ x,
                             ushort_t* __restrict__ xb, long n8) {
  long i = (long)blockIdx.x * blockDim.x + threadIdx.x;
  long stride = (long)gridDim.x * blockDim.x;
  for (; i < n8; i += stride) {
    const float4* p = (const float4*)(x + i * 8);
    float4 v0 = p[0], v1 = p[1];
    short8 o;
    o[0] = (short)f2bf(v0.x); o[1] = (short)f2bf(v0.y);
    o[2] = (short)f2bf(v0.z); o[3] = (short)f2bf(v0.w);
    o[4] = (short)f2bf(v1.x); o[5] = (short)f2bf(v1.y);
    o[6] = (short)f2bf(v1.z); o[7] = (short)f2bf(v1.w);
    *(short8*)(xb + i * 8) = o;
  }
}

// ---------- prep 2: Wt[n][k] = bf16(base[k][n] + coeff*sign) ----------
__global__ void make_wt_kernel(const float* __restrict__ base,
                               const int* __restrict__ mask,
                               const float* __restrict__ coeffp,
                               ushort_t* __restrict__ wt) {
  __shared__ ushort_t tile[32][33];
  const float c = *coeffp;
  const int n0 = blockIdx.x * 32, k0 = blockIdx.y * 32;
  const int tx = threadIdx.x, ty = threadIdx.y;
#pragma unroll
  for (int r = 0; r < 4; ++r) {
    int k = k0 + ty + r * 8;
    int n = n0 + tx;
    size_t idx = (size_t)k * N_DIM + n;
    float s = mask[idx] ? c : -c;
    tile[ty + r * 8][tx] = f2bf(base[idx] + s);
  }
  __syncthreads();
#pragma unroll
  for (int r = 0; r < 4; ++r) {
    int n = n0 + ty + r * 8;
    int k = k0 + tx;
    wt[(size_t)n * K_DIM + k] = tile[tx][ty + r * 8];
  }
}

// ---------- 256x256 bf16 GEMM: R3 structure, single-variable change ----------
// Stage stream (2 loads each): p1:(t+1,B,h1) p2:(t+1,A,h1) p3:(t+2,A,h0) p4:(t+2,B,h0).
// Waits: vmcnt(6) at p2-end and p4-end (p1-end wait of R3 removed — audit:
//   p1(t) reads Ah0[p3(t-2)], Bh0[p4(t-2)] -> forced at p4(t-1)-end (>=4-phase lead)
//   p2(t) reads Bh1[p1(t-1)]               -> forced at p4(t-1)-end (3-phase lead)
//   p3(t) reads Ah1[p2(t-1)]               -> forced at p2(t)-end   (4-phase lead)
// ). NO lgkm pre-drain (R9's regression suspect). Everything else == R3.
// Tail (round-2 fix): loop t < NT-1 with guarded stages, then vmcnt(0)+BAR and
// a peeled stage-free last K-tile.
#define FENCE asm volatile("" ::: "memory")
#define BAR   do { FENCE; __builtin_amdgcn_s_barrier(); FENCE; } while (0)
#define VW6   asm volatile("s_waitcnt vmcnt(6)" ::: "memory")
#define VW4   asm volatile("s_waitcnt vmcnt(4)" ::: "memory")
#define VW0   asm volatile("s_waitcnt vmcnt(0)" ::: "memory")

__global__ __launch_bounds__(512, 2) void gemm_bf16_256(
    const ushort_t* __restrict__ Xb,
    const ushort_t* __restrict__ Wt,
    float* __restrict__ out) {
  __shared__ ushort_t Al[2][256][64];   // 64 KiB
  __shared__ ushort_t Bl[2][256][64];   // 64 KiB

  const int tid = threadIdx.x;
  const int lane = tid & 63;
  const int w = tid >> 6;               // wave 0..7
  const int wm = w >> 2, wn = w & 3;    // 2M x 4N
  const int lrow = lane & 15, kg = lane >> 4;

  // T1: bijective XCD swizzle (512 % 8 == 0)
  const int bid = blockIdx.x;
  const int swz = (bid & 7) * 64 + (bid >> 3);
  const int bm = (swz >> 4) * 256;
  const int bn = (swz & 15) * 256;

  // staging: thread covers half-rows w*8+(lane>>3) and +64; LDS slot lane&7;
  // source chunk = slot ^ (row&7)  (pre-swizzled source; read applies same XOR)
  const int rh0 = w * 8 + (lane >> 3);
  const int srcslot = (lane & 7) ^ ((lane >> 3) & 7);
  const ushort_t* Ag = Xb + (size_t)(bm + rh0) * K_DIM + srcslot * 8;
  const ushort_t* Bg = Wt + (size_t)(bn + rh0) * K_DIM + srcslot * 8;
  char* AlB = (char*)&Al[0][0][0];
  char* BlB = (char*)&Bl[0][0][0];
  const int ldsw = w * 1024;

#define STAGE(Og, Lb, u, h) do { if ((u) < NT) {                                   \
    const ushort_t* _s0 = (Og) + (size_t)((h) * 128) * K_DIM + (size_t)(u) * 64;   \
    __builtin_amdgcn_global_load_lds((as1const_u32*)_s0,                           \
        (as3_u32*)((Lb) + ((u) & 1) * 32768 + (h) * 16384 + ldsw), 16, 0, 0);      \
    __builtin_amdgcn_global_load_lds((as1const_u32*)(_s0 + (size_t)64 * K_DIM),    \
        (as3_u32*)((Lb) + ((u) & 1) * 32768 + (h) * 16384 + ldsw + 8192), 16, 0, 0); \
  } } while (0)

  // LDS read addresses (byte): row*128 + ((kk*4+kg)^(lrow&7))*16
  const int arow = (wm * 16 + lrow) << 7;
  const int brow = (wn * 16 + lrow) << 7;
  const int sw0 = ((0 + kg) ^ (lrow & 7)) << 4;
  const int sw1 = ((4 + kg) ^ (lrow & 7)) << 4;

#define LDA(bt, mi, kk) (*(const short8*)(AlB + (bt) * 32768 + (mi) * 4096 + arow + ((kk) ? sw1 : sw0)))
#define LDB(bt, ni, kk) (*(const short8*)(BlB + (bt) * 32768 + (ni) * 8192 + brow + ((kk) ? sw1 : sw0)))
#define MFMA(a, b, c) __builtin_amdgcn_mfma_f32_16x16x32_bf16(a, b, c, 0, 0, 0)

  f32x4 acc[8][4] = {};
  short8 Ar[4][2], Br[4][2];

  // prologue: tile 0 all 4 halves + tile 1 h0 halves; vmcnt(4) -> tile-0 landed
  STAGE(Ag, AlB, 0, 0); STAGE(Bg, BlB, 0, 0);
  STAGE(Bg, BlB, 0, 1); STAGE(Ag, AlB, 0, 1);
  STAGE(Ag, AlB, 1, 0); STAGE(Bg, BlB, 1, 0);
  VW4; BAR;

  for (int t = 0; t < NT - 1; ++t) {
    const int bt = t & 1;

    // ---- phase 1: stage (t+1,B,h1); read Ah0(mi0-3)+Bh0(ni0-1); MFMA (lo,lo) ----
    STAGE(Bg, BlB, t + 1, 1);
#pragma unroll
    for (int mi = 0; mi < 4; ++mi) { Ar[mi][0] = LDA(bt, mi, 0); Ar[mi][1] = LDA(bt, mi, 1); }
#pragma unroll
    for (int ni = 0; ni < 2; ++ni) { Br[ni][0] = LDB(bt, ni, 0); Br[ni][1] = LDB(bt, ni, 1); }
    BAR;
    __builtin_amdgcn_s_setprio(1);
#pragma unroll
    for (int mi = 0; mi < 4; ++mi)
#pragma unroll
      for (int ni = 0; ni < 2; ++ni) {
        acc[mi][ni] = MFMA(Ar[mi][0], Br[ni][0], acc[mi][ni]);
        acc[mi][ni] = MFMA(Ar[mi][1], Br[ni][1], acc[mi][ni]);
      }
    __builtin_amdgcn_s_setprio(0);
    BAR;   // p1-end vmcnt removed (single change vs R3)

    // ---- phase 2: stage (t+1,A,h1); read Bh1(ni2-3); MFMA (lo,hi); VW6 ----
    STAGE(Ag, AlB, t + 1, 1);
#pragma unroll
    for (int ni = 2; ni < 4; ++ni) { Br[ni][0] = LDB(bt, ni, 0); Br[ni][1] = LDB(bt, ni, 1); }
    BAR;
    __builtin_amdgcn_s_setprio(1);
#pragma unroll
    for (int mi = 0; mi < 4; ++mi)
#pragma unroll
      for (int ni = 2; ni < 4; ++ni) {
        acc[mi][ni] = MFMA(Ar[mi][0], Br[ni][0], acc[mi][ni]);
        acc[mi][ni] = MFMA(Ar[mi][1], Br[ni][1], acc[mi][ni]);
      }
    __builtin_amdgcn_s_setprio(0);
    VW6; BAR;

    // ---- phase 3: stage (t+2,A,h0); read Ah1(mi4-7); MFMA (hi,lo) ----
    STAGE(Ag, AlB, t + 2, 0);
#pragma unroll
    for (int mi = 0; mi < 4; ++mi) { Ar[mi][0] = LDA(bt, mi + 4, 0); Ar[mi][1] = LDA(bt, mi + 4, 1); }
    BAR;
    __builtin_amdgcn_s_setprio(1);
#pragma unroll
    for (int mi = 0; mi < 4; ++mi)
#pragma unroll
      for (int ni = 0; ni < 2; ++ni) {
        acc[mi + 4][ni] = MFMA(Ar[mi][0], Br[ni][0], acc[mi + 4][ni]);
        acc[mi + 4][ni] = MFMA(Ar[mi][1], Br[ni][1], acc[mi + 4][ni]);
      }
    __builtin_amdgcn_s_setprio(0);
    BAR;

    // ---- phase 4: stage (t+2,B,h0); MFMA (hi,hi); VW6 ----
    STAGE(Bg, BlB, t + 2, 0);
    BAR;
    __builtin_amdgcn_s_setprio(1);
#pragma unroll
    for (int mi = 0; mi < 4; ++mi)
#pragma unroll
      for (int ni = 2; ni < 4; ++ni) {
        acc[mi + 4][ni] = MFMA(Ar[mi][0], Br[ni][0], acc[mi + 4][ni]);
        acc[mi + 4][ni] = MFMA(Ar[mi][1], Br[ni][1], acc[mi + 4][ni]);
      }
    __builtin_amdgcn_s_setprio(0);
    VW6; BAR;
  }

  // ---- peeled last K-tile: drain ALL DMA, then stage-free compute ----
  VW0; BAR;
  {
    const int bt = (NT - 1) & 1;
#pragma unroll
    for (int mi = 0; mi < 4; ++mi) { Ar[mi][0] = LDA(bt, mi, 0); Ar[mi][1] = LDA(bt, mi, 1); }
#pragma unroll
    for (int ni = 0; ni < 4; ++ni) { Br[ni][0] = LDB(bt, ni, 0); Br[ni][1] = LDB(bt, ni, 1); }
#pragma unroll
    for (int mi = 0; mi < 4; ++mi)
#pragma unroll
      for (int ni = 0; ni < 4; ++ni) {
        acc[mi][ni] = MFMA(Ar[mi][0], Br[ni][0], acc[mi][ni]);
        acc[mi][ni] = MFMA(Ar[mi][1], Br[ni][1], acc[mi][ni]);
      }
#pragma unroll
    for (int mi = 0; mi < 4; ++mi) { Ar[mi][0] = LDA(bt, mi + 4, 0); Ar[mi][1] = LDA(bt, mi + 4, 1); }
#pragma unroll
    for (int mi = 0; mi < 4; ++mi)
#pragma unroll
      for (int ni = 0; ni < 4; ++ni) {
        acc[mi + 4][ni] = MFMA(Ar[mi][0], Br[ni][0], acc[mi + 4][ni]);
        acc[mi + 4][ni] = MFMA(Ar[mi][1], Br[ni][1], acc[mi + 4][ni]);
      }
  }

  // epilogue: C/D layout col=lane&15, row=(lane>>4)*4+r  [m89/m91]
#pragma unroll
  for (int mi = 0; mi < 8; ++mi)
#pragma unroll
    for (int ni = 0; ni < 4; ++ni) {
      const int gr = bm + mi * 32 + wm * 16 + kg * 4;
      const int gc = bn + ni * 64 + wn * 16 + lrow;
      float* o = out + (size_t)gr * N_DIM + gc;
#pragma unroll
      for (int r = 0; r < 4; ++r) o[(size_t)r * N_DIM] = acc[mi][ni][r];
    }
}

// ---------- fallback (tiny workspace): exact f32 tiled GEMM ----------
__global__ void gemm_f32_fallback(const float* __restrict__ x,
                                  const float* __restrict__ base,
                                  const float* __restrict__ coeffp,
                                  const int* __restrict__ mask,
                                  float* __restrict__ out) {
  __shared__ float As[32][33];
  __shared__ float Bs[32][33];
  const float c = *coeffp;
  const int tx = threadIdx.x, ty = threadIdx.y;
  const int row = blockIdx.y * 32 + ty, col = blockIdx.x * 32 + tx;
  float acc = 0.f;
  for (int kt = 0; kt < K_DIM; kt += 32) {
    As[ty][tx] = x[(size_t)row * K_DIM + kt + tx];
    size_t bidx = (size_t)(kt + ty) * N_DIM + col;
    Bs[ty][tx] = base[bidx] + (mask[bidx] ? c : -c);
    __syncthreads();
#pragma unroll
    for (int k = 0; k < 32; ++k) acc += As[ty][k] * Bs[k][tx];
    __syncthreads();
  }
  out[(size_t)row * N_DIM + col] = acc;
}

extern "C" void kernel_launch(void* const* d_in, const int* in_sizes, int n_in,
                              void* d_out, int out_size, void* d_ws, size_t ws_size,
                              hipStream_t stream) {
  const float* x     = (const float*)d_in[0];
  const float* base  = (const float*)d_in[1];
  const float* coeff = (const float*)d_in[2];
  const int*   mask  = (const int*)d_in[3];
  float* out = (float*)d_out;

  const size_t xb_bytes = (size_t)M_DIM * K_DIM * sizeof(ushort_t);  // 64 MiB
  const size_t wt_bytes = (size_t)K_DIM * N_DIM * sizeof(ushort_t);  // 32 MiB

  if (ws_size >= xb_bytes + wt_bytes) {
    ushort_t* xb = (ushort_t*)d_ws;
    ushort_t* wt = (ushort_t*)((char*)d_ws + xb_bytes);
    long n8 = (long)M_DIM * K_DIM / 8;
    cvt_x_kernel<<<4096, 256, 0, stream>>>(x, xb, n8);
    make_wt_kernel<<<dim3(N_DIM / 32, K_DIM / 32), dim3(32, 8), 0, stream>>>(base, mask, coeff, wt);
    gemm_bf16_256<<<512, 512, 0, stream>>>(xb, wt, out);
  } else {
    gemm_f32_fallback<<<dim3(N_DIM / 32, M_DIM / 32), dim3(32, 32), 0, stream>>>(x, base, coeff, mask, out);
  }
}

// Round 11
// 312.775 us; speedup vs baseline: 1.0735x; 1.0496x over previous
//
#include <hip/hip_runtime.h>
#include <hip/hip_bf16.h>
#include <stdint.h>

// out[M,N] = x[M,K] @ (base + coeff*(2*mask-1))[K,N]
#define M_DIM 8192
#define K_DIM 4096
#define N_DIM 4096
#define NT (K_DIM / 64)   // 64 K-tiles of BK=64 (NT even)

typedef __attribute__((ext_vector_type(8))) short short8;
typedef __attribute__((ext_vector_type(4))) float f32x4;
typedef unsigned short ushort_t;

typedef const __attribute__((address_space(1))) unsigned int as1const_u32;
typedef __attribute__((address_space(3))) unsigned int as3_u32;

__device__ __forceinline__ unsigned short f2bf(float f) {
  unsigned int u = __float_as_uint(f);
  u += 0x7FFF + ((u >> 16) & 1);   // round-to-nearest-even
  return (unsigned short)(u >> 16);
}

// ---------- prep 1: x (f32) -> bf16, vectorized ----------
__global__ void cvt_x_kernel(const float* __restrict__ x,
                             ushort_t* __restrict__ xb, long n8) {
  long i = (long)blockIdx.x * blockDim.x + threadIdx.x;
  long stride = (long)gridDim.x * blockDim.x;
  for (; i < n8; i += stride) {
    const float4* p = (const float4*)(x + i * 8);
    float4 v0 = p[0], v1 = p[1];
    short8 o;
    o[0] = (short)f2bf(v0.x); o[1] = (short)f2bf(v0.y);
    o[2] = (short)f2bf(v0.z); o[3] = (short)f2bf(v0.w);
    o[4] = (short)f2bf(v1.x); o[5] = (short)f2bf(v1.y);
    o[6] = (short)f2bf(v1.z); o[7] = (short)f2bf(v1.w);
    *(short8*)(xb + i * 8) = o;
  }
}

// ---------- prep 2: Wt[n][k] = bf16(base[k][n] + coeff*sign) ----------
__global__ void make_wt_kernel(const float* __restrict__ base,
                               const int* __restrict__ mask,
                               const float* __restrict__ coeffp,
                               ushort_t* __restrict__ wt) {
  __shared__ ushort_t tile[32][33];
  const float c = *coeffp;
  const int n0 = blockIdx.x * 32, k0 = blockIdx.y * 32;
  const int tx = threadIdx.x, ty = threadIdx.y;
#pragma unroll
  for (int r = 0; r < 4; ++r) {
    int k = k0 + ty + r * 8;
    int n = n0 + tx;
    size_t idx = (size_t)k * N_DIM + n;
    float s = mask[idx] ? c : -c;
    tile[ty + r * 8][tx] = f2bf(base[idx] + s);
  }
  __syncthreads();
#pragma unroll
  for (int r = 0; r < 4; ++r) {
    int n = n0 + ty + r * 8;
    int k = k0 + tx;
    wt[(size_t)n * K_DIM + k] = tile[tx][ty + r * 8];
  }
}

// ---------- 256x256 bf16 GEMM: m201-faithful 8-phase / 2-K-tile schedule ----------
// Per phase: {ds_read subtile; stage 1 half-tile} -> BAR -> lgkmcnt(0) ->
// setprio(1) -> 16 MFMA -> setprio(0) -> [vmcnt(6) at ph4/ph8 only] -> BAR.
// Stage stream (each region restaged right after its read phase):
//   ph1:(t+1,A1) ph2:(t+2,A0) ph3:(t+2,B0) ph4:(t+2,B1)
//   ph5:(t+2,A1) ph6:(t+3,A0) ph7:(t+3,B0) ph8:(t+3,B1)
// Force audit: ph4-end vmcnt(6) -> completes (t+1,{A0,B0,B1,A1}) [leads 3-6ph];
// ph8-end vmcnt(6) -> completes (t+2,*) [leads 3-6ph]. Post-barrier lgkmcnt(0)
// makes each end-barrier a read-completion fence => stage-after-read is safe.
// Prologue: 7 half-tiles + vmcnt(6) (tile0 forced, 3 in flight). Epilogue:
// 4 phases for NT-2 (stage (NT-1,A1) at ph1e), vmcnt(0)+BAR, barrier-free NT-1.
#define FENCE asm volatile("" ::: "memory")
#define BAR   do { FENCE; __builtin_amdgcn_s_barrier(); FENCE; } while (0)
#define VW6   asm volatile("s_waitcnt vmcnt(6)" ::: "memory")
#define VW0   asm volatile("s_waitcnt vmcnt(0)" ::: "memory")
#define LGK0  asm volatile("s_waitcnt lgkmcnt(0)" ::: "memory")
#define SP1   __builtin_amdgcn_s_setprio(1)
#define SP0   __builtin_amdgcn_s_setprio(0)

__global__ __launch_bounds__(512, 2) void gemm_bf16_256(
    const ushort_t* __restrict__ Xb,
    const ushort_t* __restrict__ Wt,
    float* __restrict__ out) {
  __shared__ ushort_t Al[2][256][64];   // 64 KiB
  __shared__ ushort_t Bl[2][256][64];   // 64 KiB

  const int tid = threadIdx.x;
  const int lane = tid & 63;
  const int w = tid >> 6;               // wave 0..7
  const int wm = w >> 2, wn = w & 3;    // 2M x 4N
  const int lrow = lane & 15, kg = lane >> 4;

  // T1: bijective XCD swizzle (512 % 8 == 0)
  const int bid = blockIdx.x;
  const int swz = (bid & 7) * 64 + (bid >> 3);
  const int bm = (swz >> 4) * 256;
  const int bn = (swz & 15) * 256;

  // staging: thread covers half-rows w*8+(lane>>3) and +64; LDS slot lane&7;
  // source chunk = slot ^ (row&7)  (pre-swizzled source; read applies same XOR)
  const int rh0 = w * 8 + (lane >> 3);
  const int srcslot = (lane & 7) ^ ((lane >> 3) & 7);
  const ushort_t* Ag = Xb + (size_t)(bm + rh0) * K_DIM + srcslot * 8;
  const ushort_t* Bg = Wt + (size_t)(bn + rh0) * K_DIM + srcslot * 8;
  char* AlB = (char*)&Al[0][0][0];
  char* BlB = (char*)&Bl[0][0][0];
  const int ldsw = w * 1024;

#define STAGE(Og, Lb, u, h) do {                                                   \
    const ushort_t* _s0 = (Og) + (size_t)((h) * 128) * K_DIM + (size_t)(u) * 64;   \
    __builtin_amdgcn_global_load_lds((as1const_u32*)_s0,                           \
        (as3_u32*)((Lb) + ((u) & 1) * 32768 + (h) * 16384 + ldsw), 16, 0, 0);      \
    __builtin_amdgcn_global_load_lds((as1const_u32*)(_s0 + (size_t)64 * K_DIM),    \
        (as3_u32*)((Lb) + ((u) & 1) * 32768 + (h) * 16384 + ldsw + 8192), 16, 0, 0); \
  } while (0)

  // LDS read addresses (byte): row*128 + ((kk*4+kg)^(lrow&7))*16
  const int arow = (wm * 16 + lrow) << 7;
  const int brow = (wn * 16 + lrow) << 7;
  const int sw0 = ((0 + kg) ^ (lrow & 7)) << 4;
  const int sw1 = ((4 + kg) ^ (lrow & 7)) << 4;

#define LDA(bt, mi, kk) (*(const short8*)(AlB + (bt) * 32768 + (mi) * 4096 + arow + ((kk) ? sw1 : sw0)))
#define LDB(bt, ni, kk) (*(const short8*)(BlB + (bt) * 32768 + (ni) * 8192 + brow + ((kk) ? sw1 : sw0)))
#define MFMA(a, b, c) __builtin_amdgcn_mfma_f32_16x16x32_bf16(a, b, c, 0, 0, 0)

  f32x4 acc[8][4] = {};
  short8 Ar[4][2], Br[4][2];   // Ar = current A-half; Br[0..1]=B0, Br[2..3]=B1

#define RD_A4(bt, base)                                                            \
  _Pragma("unroll")                                                                \
  for (int mi = 0; mi < 4; ++mi) {                                                 \
    Ar[mi][0] = LDA(bt, (base) + mi, 0); Ar[mi][1] = LDA(bt, (base) + mi, 1);      \
  }
#define RD_B2(bt, nb)                                                              \
  _Pragma("unroll")                                                                \
  for (int ni = 0; ni < 2; ++ni) {                                                 \
    Br[(nb) + ni][0] = LDB(bt, (nb) + ni, 0); Br[(nb) + ni][1] = LDB(bt, (nb) + ni, 1); \
  }
#define MMQ(mb, nb)                                                                \
  _Pragma("unroll")                                                                \
  for (int mi = 0; mi < 4; ++mi)                                                   \
    _Pragma("unroll")                                                              \
    for (int ni = 0; ni < 2; ++ni) {                                               \
      acc[(mb) + mi][(nb) + ni] = MFMA(Ar[mi][0], Br[(nb) + ni][0], acc[(mb) + mi][(nb) + ni]); \
      acc[(mb) + mi][(nb) + ni] = MFMA(Ar[mi][1], Br[(nb) + ni][1], acc[(mb) + mi][(nb) + ni]); \
    }

  // prologue: 7 half-tiles; vmcnt(6) -> tile 0 complete, 3 halves of tile 1 in flight
  STAGE(Ag, AlB, 0, 0); STAGE(Bg, BlB, 0, 0);
  STAGE(Bg, BlB, 0, 1); STAGE(Ag, AlB, 0, 1);
  STAGE(Ag, AlB, 1, 0); STAGE(Bg, BlB, 1, 0);
  STAGE(Bg, BlB, 1, 1);
  VW6; BAR;

  for (int t = 0; t + 3 < NT; t += 2) {
    // ======== tile t (buf0) ========
    // ph1: read A0+B0; stage (t+1,A1)
    RD_A4(0, 0); RD_B2(0, 0);
    STAGE(Ag, AlB, t + 1, 1);
    BAR; LGK0; SP1; MMQ(0, 0); SP0; BAR;
    // ph2: read B1; stage (t+2,A0)
    RD_B2(0, 2);
    STAGE(Ag, AlB, t + 2, 0);
    BAR; LGK0; SP1; MMQ(0, 2); SP0; BAR;
    // ph3: read A1; stage (t+2,B0)
    RD_A4(0, 4);
    STAGE(Bg, BlB, t + 2, 0);
    BAR; LGK0; SP1; MMQ(4, 0); SP0; BAR;
    // ph4: stage (t+2,B1); ONE vmcnt per K-tile
    STAGE(Bg, BlB, t + 2, 1);
    BAR; SP1; MMQ(4, 2); SP0; VW6; BAR;

    // ======== tile t+1 (buf1) ========
    // ph5: read A0+B0; stage (t+2,A1)
    RD_A4(1, 0); RD_B2(1, 0);
    STAGE(Ag, AlB, t + 2, 1);
    BAR; LGK0; SP1; MMQ(0, 0); SP0; BAR;
    // ph6: read B1; stage (t+3,A0)
    RD_B2(1, 2);
    STAGE(Ag, AlB, t + 3, 0);
    BAR; LGK0; SP1; MMQ(0, 2); SP0; BAR;
    // ph7: read A1; stage (t+3,B0)
    RD_A4(1, 4);
    STAGE(Bg, BlB, t + 3, 0);
    BAR; LGK0; SP1; MMQ(4, 0); SP0; BAR;
    // ph8: stage (t+3,B1); vmcnt
    STAGE(Bg, BlB, t + 3, 1);
    BAR; SP1; MMQ(4, 2); SP0; VW6; BAR;
  }

  // ---- epilogue: tile NT-2 (buf0); outstanding = (NT-1,{A0,B0,B1}) ----
  RD_A4(0, 0); RD_B2(0, 0);
  STAGE(Ag, AlB, NT - 1, 1);          // last missing half (NT-1,A1)
  BAR; LGK0; SP1; MMQ(0, 0); SP0; BAR;
  RD_B2(0, 2);
  BAR; LGK0; SP1; MMQ(0, 2); SP0; BAR;
  RD_A4(0, 4);
  BAR; LGK0; SP1; MMQ(4, 0); SP0; BAR;
  SP1; MMQ(4, 2); SP0;
  VW0; BAR;                           // drain all of tile NT-1
  // ---- tile NT-1 (buf1): barrier-free full compute ----
  RD_A4(1, 0); RD_B2(1, 0); RD_B2(1, 2);
  MMQ(0, 0); MMQ(0, 2);
  RD_A4(1, 4);
  MMQ(4, 0); MMQ(4, 2);

  // epilogue: C/D layout col=lane&15, row=(lane>>4)*4+r  [m89/m91]
#pragma unroll
  for (int mi = 0; mi < 8; ++mi)
#pragma unroll
    for (int ni = 0; ni < 4; ++ni) {
      const int gr = bm + mi * 32 + wm * 16 + kg * 4;
      const int gc = bn + ni * 64 + wn * 16 + lrow;
      float* o = out + (size_t)gr * N_DIM + gc;
#pragma unroll
      for (int r = 0; r < 4; ++r) o[(size_t)r * N_DIM] = acc[mi][ni][r];
    }
}

// ---------- fallback (tiny workspace): exact f32 tiled GEMM ----------
__global__ void gemm_f32_fallback(const float* __restrict__ x,
                                  const float* __restrict__ base,
                                  const float* __restrict__ coeffp,
                                  const int* __restrict__ mask,
                                  float* __restrict__ out) {
  __shared__ float As[32][33];
  __shared__ float Bs[32][33];
  const float c = *coeffp;
  const int tx = threadIdx.x, ty = threadIdx.y;
  const int row = blockIdx.y * 32 + ty, col = blockIdx.x * 32 + tx;
  float acc = 0.f;
  for (int kt = 0; kt < K_DIM; kt += 32) {
    As[ty][tx] = x[(size_t)row * K_DIM + kt + tx];
    size_t bidx = (size_t)(kt + ty) * N_DIM + col;
    Bs[ty][tx] = base[bidx] + (mask[bidx] ? c : -c);
    __syncthreads();
#pragma unroll
    for (int k = 0; k < 32; ++k) acc += As[ty][k] * Bs[k][tx];
    __syncthreads();
  }
  out[(size_t)row * N_DIM + col] = acc;
}

extern "C" void kernel_launch(void* const* d_in, const int* in_sizes, int n_in,
                              void* d_out, int out_size, void* d_ws, size_t ws_size,
                              hipStream_t stream) {
  const float* x     = (const float*)d_in[0];
  const float* base  = (const float*)d_in[1];
  const float* coeff = (const float*)d_in[2];
  const int*   mask  = (const int*)d_in[3];
  float* out = (float*)d_out;

  const size_t xb_bytes = (size_t)M_DIM * K_DIM * sizeof(ushort_t);  // 64 MiB
  const size_t wt_bytes = (size_t)K_DIM * N_DIM * sizeof(ushort_t);  // 32 MiB

  if (ws_size >= xb_bytes + wt_bytes) {
    ushort_t* xb = (ushort_t*)d_ws;
    ushort_t* wt = (ushort_t*)((char*)d_ws + xb_bytes);
    long n8 = (long)M_DIM * K_DIM / 8;
    cvt_x_kernel<<<4096, 256, 0, stream>>>(x, xb, n8);
    make_wt_kernel<<<dim3(N_DIM / 32, K_DIM / 32), dim3(32, 8), 0, stream>>>(base, mask, coeff, wt);
    gemm_bf16_256<<<512, 512, 0, stream>>>(xb, wt, out);
  } else {
    gemm_f32_fallback<<<dim3(N_DIM / 32, M_DIM / 32), dim3(32, 32), 0, stream>>>(x, base, coeff, mask, out);
  }
}